// Round 10
// baseline (480.565 us; speedup 1.0000x reference)
//
#include <hip/hip_runtime.h>
#include <hip/hip_bf16.h>

// LinearPreMix: qkv = x @ W_qkv^T, split to q,k,v, reshape [B,S,E]->[B,H,S,DK]
// Pass 1: cast x,W fp32->bf16 into d_ws.
// Pass 2: r10 — TWO independent blocks per CU (the r4-r9 diagnosis: lockstep
//         barriers serialize LDS-read and MFMA regions chip-wide; independent
//         block barriers let one block's MFMA cover the other's LDS/stage).
//         Block = 128x256, 8 waves of 64x64 (acc 64 -> ~116 VGPR -> 4 waves/
//         SIMD), BK=32 ring-2 static LDS 48 KB/block (96 KB/CU -> 2 blocks),
//         ONE barrier per phase, stage-1-ahead with W_V0.

constexpr int Bb = 4, Ss = 4096, Ee = 2048, Hh = 16, Dk = 128;
constexpr int Mm = Bb * Ss;   // 16384
constexpr int Nn = 3 * Ee;    // 6144
constexpr int Kk = Ee;        // 2048

typedef __bf16 bf16_t;
typedef __bf16 bf16x8 __attribute__((ext_vector_type(8)));
typedef float  f32x4  __attribute__((ext_vector_type(4)));

// ---------------------------------------------------------------- cast pass
__global__ __launch_bounds__(256)
void cast_f32_to_bf16(const float* __restrict__ x, const float* __restrict__ w,
                      bf16_t* __restrict__ xb, bf16_t* __restrict__ wb)
{
    const long XG = (long)Mm * Kk / 8;
    const long TG = XG + (long)Nn * Kk / 8;
    const long stride = (long)gridDim.x * blockDim.x;
    for (long g = (long)blockIdx.x * blockDim.x + threadIdx.x; g < TG; g += stride) {
        const float* s; bf16_t* d;
        if (g < XG) { s = x + g * 8;        d = xb + g * 8; }
        else        { s = w + (g - XG) * 8; d = wb + (g - XG) * 8; }
        f32x4 lo = *(const f32x4*)s;
        f32x4 hi = *(const f32x4*)(s + 4);
        bf16x8 o;
#pragma unroll
        for (int j = 0; j < 4; ++j) { o[j] = (bf16_t)lo[j]; o[j + 4] = (bf16_t)hi[j]; }
        *(bf16x8*)d = o;
    }
}

// --------------------------------------- 2-blocks/CU 128x256 ring-2 GEMM
constexpr int BM = 128, BN = 256;
constexpr int NBM = Mm / BM;     // 128
constexpr int NBN = Nn / BN;     // 24
constexpr int NWG = NBM * NBN;   // 3072
constexpr int NPH = Kk / 32;     // 64 K32 phases

#define GLL16(GSRC, LDST) \
  __builtin_amdgcn_global_load_lds((const __attribute__((address_space(1))) void*)(GSRC), \
                                   (__attribute__((address_space(3))) void*)(LDST), 16, 0, 0)

#define W_V0 asm volatile("s_waitcnt vmcnt(0)" ::: "memory")

// phase: read slot S frags | stage slice P+1 -> slot S^1 | 16 MFMA | W_V0 | bar
#define PHZ(S, P) do { \
    bf16x8 a[4], b[4]; \
    _Pragma("unroll") \
    for (int mf = 0; mf < 4; ++mf) { \
        int r = wm * 64 + mf * 16 + (lane & 15); \
        int q = r * 4 + (kc ^ ((r >> 1) & 3)); \
        a[mf] = *(const bf16x8*)(sA + (S) * 4096 + q * 8); \
    } \
    _Pragma("unroll") \
    for (int nf = 0; nf < 4; ++nf) { \
        int cr = wn * 64 + nf * 16 + (lane & 15); \
        int q = cr * 4 + (kc ^ ((cr >> 1) & 3)); \
        b[nf] = *(const bf16x8*)(sB + (S) * 8192 + q * 8); \
    } \
    { \
        const int kn = (((P) + 1) * 32) & 2047; \
        GLL16(srcA  + kn, sA + ((S) ^ 1) * 4096 + tid * 8); \
        GLL16(srcB0 + kn, sB + ((S) ^ 1) * 8192 + tid * 8); \
        GLL16(srcB1 + kn, sB + ((S) ^ 1) * 8192 + 4096 + tid * 8); \
    } \
    __builtin_amdgcn_sched_barrier(0); \
    __builtin_amdgcn_s_setprio(1); \
    _Pragma("unroll") \
    for (int mf = 0; mf < 4; ++mf) { \
        _Pragma("unroll") \
        for (int nf = 0; nf < 4; ++nf) \
            acc[mf][nf] = __builtin_amdgcn_mfma_f32_16x16x32_bf16( \
                a[mf], b[nf], acc[mf][nf], 0, 0, 0); \
    } \
    __builtin_amdgcn_s_setprio(0); \
    W_V0; \
    __builtin_amdgcn_sched_barrier(0); \
    __builtin_amdgcn_s_barrier(); \
} while (0)

__global__ __launch_bounds__(512, 4)
void qkv_tlp2(const bf16_t* __restrict__ xb, const bf16_t* __restrict__ wb,
              float* __restrict__ out)
{
    // ring-2 static LDS: A 2 x (128x32) = 16 KB, B 2 x (256x32) = 32 KB
    __shared__ __attribute__((aligned(16))) bf16_t sA[2 * 4096];
    __shared__ __attribute__((aligned(16))) bf16_t sB[2 * 8192];

    const int tid  = threadIdx.x;
    const int lane = tid & 63;
    const int wid  = tid >> 6;     // 0..7
    const int wm   = wid & 1;      // 0..1 (64-row half of 128)
    const int wn   = wid >> 1;     // 0..3 (64-col quarter of 256)
    const int kc   = lane >> 4;    // frag k-chunk 0..3

    // L2-cooperative mapping: each XCD owns a 16-row bm stripe, bn-major walk.
    const int xcd = blockIdx.x & 7;
    const int i   = blockIdx.x >> 3;        // 0..383
    const int bm  = xcd * 16 + (i & 15);    // 0..127
    const int bn  = i >> 4;                 // 0..23
    const int m0 = bm * BM, n0 = bn * BN;

    // pre-swizzled staging sources (linear LDS dest + swizzled global source).
    // chunk c: row r=c>>2, stored pos p=c&3, logical col = p ^ ((r>>1)&3).
    const int r0  = tid >> 2;                        // 0..127
    const int cl0 = (tid & 3) ^ ((r0 >> 1) & 3);
    const bf16_t* srcA  = xb + (size_t)(m0 + r0) * Kk + cl0 * 8;
    const bf16_t* srcB0 = wb + (size_t)(n0 + r0) * Kk + cl0 * 8;
    const bf16_t* srcB1 = srcB0 + (size_t)128 * Kk;

    f32x4 acc[4][4] = {};

    // prologue: stage slice 0 into slot 0
    GLL16(srcA,  sA + tid * 8);
    GLL16(srcB0, sB + tid * 8);
    GLL16(srcB1, sB + 4096 + tid * 8);
    W_V0;
    __builtin_amdgcn_s_barrier();

#pragma unroll 1
    for (int p = 0; p < NPH; p += 2) {
        PHZ(0, p);
        PHZ(1, p + 1);
    }

    // epilogue: wave tile 64x64 at (m0+wm*64, n0+wn*64); head = wn>>1.
    const int which = n0 >> 11;
    const int hh    = ((n0 & (Ee - 1)) >> 7) + (wn >> 1);
    const int bbx   = m0 >> 12;
    const int srow  = (m0 & (Ss - 1)) + wm * 64;
    float* obase = out + (((size_t)(which * Bb + bbx) * Hh + hh) * Ss + srow) * Dk
                 + (wn & 1) * 64;

#pragma unroll
    for (int mf = 0; mf < 4; ++mf)
#pragma unroll
        for (int r = 0; r < 4; ++r)
#pragma unroll
            for (int nf = 0; nf < 4; ++nf) {
                const int row = mf * 16 + (lane >> 4) * 4 + r;
                const int col = nf * 16 + (lane & 15);
                __builtin_nontemporal_store(acc[mf][nf][r],
                                            &obase[(size_t)row * Dk + col]);
            }
}

// ------------------------------------------- fallback (fp32 reg staging)
constexpr int FTM = 128, FTN = 128, FTK = 64;
constexpr int FNKT = Kk / FTK;

__global__ __launch_bounds__(256, 2)
void qkv_gemm_fb(const float* __restrict__ x, const float* __restrict__ w,
                 float* __restrict__ out)
{
    __shared__ __attribute__((aligned(16))) bf16_t lA[2][FTM * FTK];
    __shared__ __attribute__((aligned(16))) bf16_t lB[2][FTN * FTK];

    const int tid = threadIdx.x, lane = tid & 63, wid = tid >> 6;
    const int wm = wid >> 1, wn = wid & 1;
    const int n0 = blockIdx.x * FTN, m0 = blockIdx.y * FTM;
    f32x4 ra[8], rb[8];

    auto load_regs = [&](int kt) {
        const int k0 = kt * FTK;
#pragma unroll
        for (int i = 0; i < 4; ++i) {
            const int c = tid + i * 256, row = c >> 3, cir = c & 7;
            const float* pa = x + (size_t)(m0 + row) * Kk + k0 + cir * 8;
            const float* pb = w + (size_t)(n0 + row) * Kk + k0 + cir * 8;
            ra[i*2+0] = *(const f32x4*)(pa); ra[i*2+1] = *(const f32x4*)(pa+4);
            rb[i*2+0] = *(const f32x4*)(pb); rb[i*2+1] = *(const f32x4*)(pb+4);
        }
    };
    auto store_lds = [&](int buf) {
#pragma unroll
        for (int i = 0; i < 4; ++i) {
            const int c = tid + i * 256, row = c >> 3, cir = c & 7;
            const int chunk = row * 8 + (cir ^ (row & 7));
            bf16x8 va, vb;
#pragma unroll
            for (int j = 0; j < 4; ++j) {
                va[j] = (bf16_t)ra[i*2+0][j]; va[j+4] = (bf16_t)ra[i*2+1][j];
                vb[j] = (bf16_t)rb[i*2+0][j]; vb[j+4] = (bf16_t)rb[i*2+1][j];
            }
            *(bf16x8*)(&lA[buf][chunk*8]) = va;
            *(bf16x8*)(&lB[buf][chunk*8]) = vb;
        }
    };
    f32x4 acc[4][4] = {};
    auto compute = [&](int buf) {
#pragma unroll
        for (int ks = 0; ks < 2; ++ks) {
            bf16x8 af[4], bfr[4];
#pragma unroll
            for (int mi = 0; mi < 4; ++mi) {
                const int row = wm*64 + mi*16 + (lane & 15);
                const int cir = ks*4 + (lane >> 4);
                af[mi] = *(const bf16x8*)(&lA[buf][(row*8 + (cir ^ (row & 7)))*8]);
            }
#pragma unroll
            for (int ni = 0; ni < 4; ++ni) {
                const int row = wn*64 + ni*16 + (lane & 15);
                const int cir = ks*4 + (lane >> 4);
                bfr[ni] = *(const bf16x8*)(&lB[buf][(row*8 + (cir ^ (row & 7)))*8]);
            }
#pragma unroll
            for (int mi = 0; mi < 4; ++mi)
#pragma unroll
                for (int ni = 0; ni < 4; ++ni)
                    acc[mi][ni] = __builtin_amdgcn_mfma_f32_16x16x32_bf16(af[mi], bfr[ni], acc[mi][ni], 0, 0, 0);
        }
    };

    load_regs(0); store_lds(0);
    int cur = 0;
#pragma unroll 1
    for (int kt = 0; kt < FNKT; ++kt) {
        __syncthreads();
        if (kt + 1 < FNKT) load_regs(kt + 1);
        compute(cur);
        if (kt + 1 < FNKT) store_lds(cur ^ 1);
        cur ^= 1;
    }
    const int b = m0 / Ss, s0g = m0 % Ss;
    const int which = n0 >> 11, h = (n0 & (Ee - 1)) >> 7;
    float* obase = out + ((size_t)((which * Bb + b) * Hh + h) * Ss + s0g) * Dk;
#pragma unroll
    for (int mi = 0; mi < 4; ++mi)
#pragma unroll
        for (int ni = 0; ni < 4; ++ni)
#pragma unroll
            for (int r = 0; r < 4; ++r) {
                const int rowL = wm*64 + mi*16 + (lane >> 4)*4 + r;
                const int colL = wn*64 + ni*16 + (lane & 15);
                obase[(size_t)rowL * Dk + colL] = acc[mi][ni][r];
            }
}

// ---------------------------------------------------------------- launcher
extern "C" void kernel_launch(void* const* d_in, const int* in_sizes, int n_in,
                              void* d_out, int out_size, void* d_ws, size_t ws_size,
                              hipStream_t stream) {
    const float* x = (const float*)d_in[0];
    const float* w = (const float*)d_in[1];
    float* out = (float*)d_out;

    const size_t xb_bytes = (size_t)Mm * Kk * 2;
    const size_t wb_bytes = (size_t)Nn * Kk * 2;

    if (ws_size >= xb_bytes + wb_bytes) {
        bf16_t* xb = (bf16_t*)d_ws;
        bf16_t* wb = (bf16_t*)((char*)d_ws + xb_bytes);
        cast_f32_to_bf16<<<2048, 256, 0, stream>>>(x, w, xb, wb);
        qkv_tlp2<<<NWG, 512, 0, stream>>>(xb, wb, out);
    } else {
        dim3 grid(Nn / FTN, Mm / FTM);
        qkv_gemm_fb<<<grid, dim3(256), 0, stream>>>(x, w, out);
    }
}

// Round 11
// 473.723 us; speedup vs baseline: 1.0144x; 1.0144x over previous
//
#include <hip/hip_runtime.h>
#include <hip/hip_bf16.h>

// LinearPreMix: qkv = x @ W_qkv^T, split to q,k,v, reshape [B,S,E]->[B,H,S,DK]
// Pass 1: cast x,W fp32->bf16 into d_ws.
// Pass 2: r11 — 2 independent blocks/CU WITH the counted-vmcnt pipeline:
//         block = 128x256 (8 waves of 64x64), ring-3 of K32 slices (72 KB LDS
//         -> 2 blocks/CU), per phase {ds_read frags + 3xGLL stage(p+2) |
//         barrier | lgkm(0) | 16 MFMA | W_V3 | barrier}. r10 failed because
//         its W_V0-per-phase exposed GLL latency every phase; this keeps
//         1-slice vmcnt slack so only cross-block overlap is being tested.

constexpr int Bb = 4, Ss = 4096, Ee = 2048, Hh = 16, Dk = 128;
constexpr int Mm = Bb * Ss;   // 16384
constexpr int Nn = 3 * Ee;    // 6144
constexpr int Kk = Ee;        // 2048

typedef __bf16 bf16_t;
typedef __bf16 bf16x8 __attribute__((ext_vector_type(8)));
typedef float  f32x4  __attribute__((ext_vector_type(4)));

// ---------------------------------------------------------------- cast pass
__global__ __launch_bounds__(256)
void cast_f32_to_bf16(const float* __restrict__ x, const float* __restrict__ w,
                      bf16_t* __restrict__ xb, bf16_t* __restrict__ wb)
{
    const long XG = (long)Mm * Kk / 8;
    const long TG = XG + (long)Nn * Kk / 8;
    const long stride = (long)gridDim.x * blockDim.x;
    for (long g = (long)blockIdx.x * blockDim.x + threadIdx.x; g < TG; g += stride) {
        const float* s; bf16_t* d;
        if (g < XG) { s = x + g * 8;        d = xb + g * 8; }
        else        { s = w + (g - XG) * 8; d = wb + (g - XG) * 8; }
        f32x4 lo = *(const f32x4*)s;
        f32x4 hi = *(const f32x4*)(s + 4);
        bf16x8 o;
#pragma unroll
        for (int j = 0; j < 4; ++j) { o[j] = (bf16_t)lo[j]; o[j + 4] = (bf16_t)hi[j]; }
        *(bf16x8*)d = o;
    }
}

// ------------------------------ 2-blocks/CU 128x256 ring-3 counted pipeline
constexpr int BM = 128, BN = 256;
constexpr int NBM = Mm / BM;     // 128
constexpr int NBN = Nn / BN;     // 24
constexpr int NWG = NBM * NBN;   // 3072
constexpr int NPH = Kk / 32;     // 64 K32 phases

#define GLL16(GSRC, LDST) \
  __builtin_amdgcn_global_load_lds((const __attribute__((address_space(1))) void*)(GSRC), \
                                   (__attribute__((address_space(3))) void*)(LDST), 16, 0, 0)

#define W_V3 asm volatile("s_waitcnt vmcnt(3)" ::: "memory")
#define W_V0 asm volatile("s_waitcnt vmcnt(0)" ::: "memory")

// stage slice (k-offset KN) into slot SS: 3 GLL16 per thread
#define STG3(SS, KN) do { \
    GLL16(srcA  + (KN), sA + (SS) * 4096 + tid * 8); \
    GLL16(srcB0 + (KN), sB + (SS) * 8192 + tid * 8); \
    GLL16(srcB1 + (KN), sB + (SS) * 8192 + 4096 + tid * 8); \
} while (0)

// phase: read slot RS frags | stage | barrier | lgkm0 | 16 MFMA | WT | barrier
#define PHX(RS, STG_STMT, WT) do { \
    bf16x8 a[4], b[4]; \
    _Pragma("unroll") \
    for (int mf = 0; mf < 4; ++mf) { \
        int r = wm * 64 + mf * 16 + (lane & 15); \
        int q = r * 4 + (kc ^ ((r >> 1) & 3)); \
        a[mf] = *(const bf16x8*)(sA + (RS) * 4096 + q * 8); \
    } \
    _Pragma("unroll") \
    for (int nf = 0; nf < 4; ++nf) { \
        int cr = wn * 64 + nf * 16 + (lane & 15); \
        int q = cr * 4 + (kc ^ ((cr >> 1) & 3)); \
        b[nf] = *(const bf16x8*)(sB + (RS) * 8192 + q * 8); \
    } \
    STG_STMT; \
    __builtin_amdgcn_sched_barrier(0); \
    __builtin_amdgcn_s_barrier(); \
    asm volatile("s_waitcnt lgkmcnt(0)" ::: "memory"); \
    __builtin_amdgcn_sched_barrier(0); \
    __builtin_amdgcn_s_setprio(1); \
    _Pragma("unroll") \
    for (int mf = 0; mf < 4; ++mf) { \
        _Pragma("unroll") \
        for (int nf = 0; nf < 4; ++nf) \
            acc[mf][nf] = __builtin_amdgcn_mfma_f32_16x16x32_bf16( \
                a[mf], b[nf], acc[mf][nf], 0, 0, 0); \
    } \
    __builtin_amdgcn_s_setprio(0); \
    WT; \
    __builtin_amdgcn_sched_barrier(0); \
    __builtin_amdgcn_s_barrier(); \
} while (0)

#define NOSTG ((void)0)
#define NOWT  ((void)0)

__global__ __launch_bounds__(512, 4)
void qkv_tlp3(const bf16_t* __restrict__ xb, const bf16_t* __restrict__ wb,
              float* __restrict__ out)
{
    // ring-3 LDS: A 3 x (128x32) = 24 KB, B 3 x (256x32) = 48 KB -> 72 KB
    extern __shared__ __attribute__((aligned(16))) char smem_raw[];
    bf16_t* sA = (bf16_t*)smem_raw;                  // 3 * 4096 bf16
    bf16_t* sB = (bf16_t*)(smem_raw + 24576);        // 3 * 8192 bf16

    const int tid  = threadIdx.x;
    const int lane = tid & 63;
    const int wid  = tid >> 6;     // 0..7
    const int wm   = wid & 1;      // 0..1 (64-row half of 128)
    const int wn   = wid >> 1;     // 0..3 (64-col quarter of 256)
    const int kc   = lane >> 4;    // frag k-chunk 0..3

    // L2-cooperative mapping: each XCD owns a 16-row bm stripe, bn-major walk.
    const int xcd = blockIdx.x & 7;
    const int i   = blockIdx.x >> 3;        // 0..383
    const int bm  = xcd * 16 + (i & 15);    // 0..127
    const int bn  = i >> 4;                 // 0..23
    const int m0 = bm * BM, n0 = bn * BN;

    // pre-swizzled staging sources (linear LDS dest + swizzled global source)
    const int r0  = tid >> 2;                        // 0..127
    const int cl0 = (tid & 3) ^ ((r0 >> 1) & 3);
    const bf16_t* srcA  = xb + (size_t)(m0 + r0) * Kk + cl0 * 8;
    const bf16_t* srcB0 = wb + (size_t)(n0 + r0) * Kk + cl0 * 8;
    const bf16_t* srcB1 = srcB0 + (size_t)128 * Kk;

    f32x4 acc[4][4] = {};

    // prologue: stage slices 0,1 into slots 0,1; confirm slice 0
    STG3(0, 0);
    STG3(1, 32);
    W_V3;
    __builtin_amdgcn_s_barrier();

    // 21 triples = phases 0..62; phase p stages slice p+2 (slot (p+2)%3).
    // Triple it=20 stages slices 62,63,64 (64 wraps to k=0: harmless junk
    // into slot 1 after its last read; keeps vmcnt accounting uniform).
#pragma unroll 1
    for (int it = 0; it < 21; ++it) {
        const int p = it * 3;
        PHX(0, STG3(2, ((p + 2) * 32) & 2047), W_V3);
        PHX(1, STG3(0, ((p + 3) * 32) & 2047), W_V3);
        PHX(2, STG3(1, ((p + 4) * 32) & 2047), W_V3);
    }
    // final phase 63: slot 0, no stage, no wait
    PHX(0, NOSTG, NOWT);

    // drain in-flight junk GLL before exit (next block reuses this LDS)
    W_V0;

    // epilogue: wave tile 64x64; head = wn>>1; nt line-contiguous stores.
    const int which = n0 >> 11;
    const int hh    = ((n0 & (Ee - 1)) >> 7) + (wn >> 1);
    const int bbx   = m0 >> 12;
    const int srow  = (m0 & (Ss - 1)) + wm * 64;
    float* obase = out + (((size_t)(which * Bb + bbx) * Hh + hh) * Ss + srow) * Dk
                 + (wn & 1) * 64;

#pragma unroll
    for (int mf = 0; mf < 4; ++mf)
#pragma unroll
        for (int r = 0; r < 4; ++r)
#pragma unroll
            for (int nf = 0; nf < 4; ++nf) {
                const int row = mf * 16 + (lane >> 4) * 4 + r;
                const int col = nf * 16 + (lane & 15);
                __builtin_nontemporal_store(acc[mf][nf][r],
                                            &obase[(size_t)row * Dk + col]);
            }
}

// ------------------------------------------- fallback (fp32 reg staging)
constexpr int FTM = 128, FTN = 128, FTK = 64;
constexpr int FNKT = Kk / FTK;

__global__ __launch_bounds__(256, 2)
void qkv_gemm_fb(const float* __restrict__ x, const float* __restrict__ w,
                 float* __restrict__ out)
{
    __shared__ __attribute__((aligned(16))) bf16_t lA[2][FTM * FTK];
    __shared__ __attribute__((aligned(16))) bf16_t lB[2][FTN * FTK];

    const int tid = threadIdx.x, lane = tid & 63, wid = tid >> 6;
    const int wm = wid >> 1, wn = wid & 1;
    const int n0 = blockIdx.x * FTN, m0 = blockIdx.y * FTM;
    f32x4 ra[8], rb[8];

    auto load_regs = [&](int kt) {
        const int k0 = kt * FTK;
#pragma unroll
        for (int i = 0; i < 4; ++i) {
            const int c = tid + i * 256, row = c >> 3, cir = c & 7;
            const float* pa = x + (size_t)(m0 + row) * Kk + k0 + cir * 8;
            const float* pb = w + (size_t)(n0 + row) * Kk + k0 + cir * 8;
            ra[i*2+0] = *(const f32x4*)(pa); ra[i*2+1] = *(const f32x4*)(pa+4);
            rb[i*2+0] = *(const f32x4*)(pb); rb[i*2+1] = *(const f32x4*)(pb+4);
        }
    };
    auto store_lds = [&](int buf) {
#pragma unroll
        for (int i = 0; i < 4; ++i) {
            const int c = tid + i * 256, row = c >> 3, cir = c & 7;
            const int chunk = row * 8 + (cir ^ (row & 7));
            bf16x8 va, vb;
#pragma unroll
            for (int j = 0; j < 4; ++j) {
                va[j] = (bf16_t)ra[i*2+0][j]; va[j+4] = (bf16_t)ra[i*2+1][j];
                vb[j] = (bf16_t)rb[i*2+0][j]; vb[j+4] = (bf16_t)rb[i*2+1][j];
            }
            *(bf16x8*)(&lA[buf][chunk*8]) = va;
            *(bf16x8*)(&lB[buf][chunk*8]) = vb;
        }
    };
    f32x4 acc[4][4] = {};
    auto compute = [&](int buf) {
#pragma unroll
        for (int ks = 0; ks < 2; ++ks) {
            bf16x8 af[4], bfr[4];
#pragma unroll
            for (int mi = 0; mi < 4; ++mi) {
                const int row = wm*64 + mi*16 + (lane & 15);
                const int cir = ks*4 + (lane >> 4);
                af[mi] = *(const bf16x8*)(&lA[buf][(row*8 + (cir ^ (row & 7)))*8]);
            }
#pragma unroll
            for (int ni = 0; ni < 4; ++ni) {
                const int row = wn*64 + ni*16 + (lane & 15);
                const int cir = ks*4 + (lane >> 4);
                bfr[ni] = *(const bf16x8*)(&lB[buf][(row*8 + (cir ^ (row & 7)))*8]);
            }
#pragma unroll
            for (int mi = 0; mi < 4; ++mi)
#pragma unroll
                for (int ni = 0; ni < 4; ++ni)
                    acc[mi][ni] = __builtin_amdgcn_mfma_f32_16x16x32_bf16(af[mi], bfr[ni], acc[mi][ni], 0, 0, 0);
        }
    };

    load_regs(0); store_lds(0);
    int cur = 0;
#pragma unroll 1
    for (int kt = 0; kt < FNKT; ++kt) {
        __syncthreads();
        if (kt + 1 < FNKT) load_regs(kt + 1);
        compute(cur);
        if (kt + 1 < FNKT) store_lds(cur ^ 1);
        cur ^= 1;
    }
    const int b = m0 / Ss, s0g = m0 % Ss;
    const int which = n0 >> 11, h = (n0 & (Ee - 1)) >> 7;
    float* obase = out + ((size_t)((which * Bb + b) * Hh + h) * Ss + s0g) * Dk;
#pragma unroll
    for (int mi = 0; mi < 4; ++mi)
#pragma unroll
        for (int ni = 0; ni < 4; ++ni)
#pragma unroll
            for (int r = 0; r < 4; ++r) {
                const int rowL = wm*64 + mi*16 + (lane >> 4)*4 + r;
                const int colL = wn*64 + ni*16 + (lane & 15);
                obase[(size_t)rowL * Dk + colL] = acc[mi][ni][r];
            }
}

// ---------------------------------------------------------------- launcher
extern "C" void kernel_launch(void* const* d_in, const int* in_sizes, int n_in,
                              void* d_out, int out_size, void* d_ws, size_t ws_size,
                              hipStream_t stream) {
    const float* x = (const float*)d_in[0];
    const float* w = (const float*)d_in[1];
    float* out = (float*)d_out;

    const size_t xb_bytes = (size_t)Mm * Kk * 2;
    const size_t wb_bytes = (size_t)Nn * Kk * 2;

    if (ws_size >= xb_bytes + wb_bytes) {
        bf16_t* xb = (bf16_t*)d_ws;
        bf16_t* wb = (bf16_t*)((char*)d_ws + xb_bytes);
        cast_f32_to_bf16<<<2048, 256, 0, stream>>>(x, w, xb, wb);
        hipFuncSetAttribute((const void*)qkv_tlp3,
                            hipFuncAttributeMaxDynamicSharedMemorySize, 73728);
        qkv_tlp3<<<NWG, 512, 73728, stream>>>(xb, wb, out);
    } else {
        dim3 grid(Nn / FTN, Mm / FTM);
        qkv_gemm_fb<<<grid, dim3(256), 0, stream>>>(x, w, out);
    }
}

// Round 12
// 435.695 us; speedup vs baseline: 1.1030x; 1.0873x over previous
//
#include <hip/hip_runtime.h>
#include <hip/hip_bf16.h>

// LinearPreMix: qkv = x @ W_qkv^T, split to q,k,v, reshape [B,S,E]->[B,H,S,DK]
// Pass 1: cast x,W fp32->bf16 into d_ws.
// Pass 2: 256x256 8-phase counted-vmcnt bf16 MFMA GEMM (m201 template).
// r12: REMOVE all sched_barrier(0) pins and the explicit bulk lgkmcnt(0)
//      (m141: order-pinning = 510 vs 874 TF). Compiler-visible ds_reads get
//      automatic counted lgkm waits -> first MFMAs start while later reads
//      are in flight (the LDS/MFMA overlap r4-r11 lacked). Otherwise = r6:
//      L2-coop XCD mapping, W_V4@phases 4/8, setprio, nt epilogue.

constexpr int Bb = 4, Ss = 4096, Ee = 2048, Hh = 16, Dk = 128;
constexpr int Mm = Bb * Ss;   // 16384
constexpr int Nn = 3 * Ee;    // 6144
constexpr int Kk = Ee;        // 2048

typedef __bf16 bf16_t;
typedef __bf16 bf16x8 __attribute__((ext_vector_type(8)));
typedef float  f32x4  __attribute__((ext_vector_type(4)));

// ---------------------------------------------------------------- cast pass
__global__ __launch_bounds__(256)
void cast_f32_to_bf16(const float* __restrict__ x, const float* __restrict__ w,
                      bf16_t* __restrict__ xb, bf16_t* __restrict__ wb)
{
    const long XG = (long)Mm * Kk / 8;
    const long TG = XG + (long)Nn * Kk / 8;
    const long stride = (long)gridDim.x * blockDim.x;
    for (long g = (long)blockIdx.x * blockDim.x + threadIdx.x; g < TG; g += stride) {
        const float* s; bf16_t* d;
        if (g < XG) { s = x + g * 8;        d = xb + g * 8; }
        else        { s = w + (g - XG) * 8; d = wb + (g - XG) * 8; }
        f32x4 lo = *(const f32x4*)s;
        f32x4 hi = *(const f32x4*)(s + 4);
        bf16x8 o;
#pragma unroll
        for (int j = 0; j < 4; ++j) { o[j] = (bf16_t)lo[j]; o[j + 4] = (bf16_t)hi[j]; }
        *(bf16x8*)d = o;
    }
}

// ------------------------------------------------------- 8-phase 256² GEMM
constexpr int BM = 256, BN = 256, BK = 64;
constexpr int NBM = Mm / BM;          // 64
constexpr int NBN = Nn / BN;          // 24
constexpr int NWG = NBM * NBN;        // 1536
constexpr int NITER = (Kk / BK) / 2;  // 16 octets

#define GLL16(GSRC, LDST) \
  __builtin_amdgcn_global_load_lds((const __attribute__((address_space(1))) void*)(GSRC), \
                                   (__attribute__((address_space(3))) void*)(LDST), 16, 0, 0)

#define STAGE_A(BUF, KH, KOFS) do { \
    bf16_t* _d = sA + ((BUF) * 2 + (KH)) * 8192 + wid * 512; \
    GLL16(srcA0 + (KOFS), _d); \
    GLL16(srcA1 + (KOFS), _d + 4096); \
} while (0)

#define STAGE_B(BUF, KH, KOFS) do { \
    bf16_t* _d = sB + ((BUF) * 2 + (KH)) * 8192 + wid * 512; \
    GLL16(srcB0 + (KOFS), _d); \
    GLL16(srcB1 + (KOFS), _d + 4096); \
} while (0)

#define NO_STAGE ((void)0)
#define W_NOW    ((void)0)
#define W_V4     asm volatile("s_waitcnt vmcnt(4)" ::: "memory")

// phase: ds-reads | stage | barrier | setprio+MFMA (compiler inserts counted
// lgkm waits; free to interleave) | counted vmcnt | barrier.  NO sched_barrier,
// NO bulk lgkmcnt(0) (m141: pinning costs 1.7x).
#define PHASE(BUF, KS, MH, LOADB, STAGE, WAIT) do { \
    bf16x8 a[4]; \
    _Pragma("unroll") \
    for (int mf = 0; mf < 4; ++mf) { \
        int r = wm * 128 + (MH) * 64 + mf * 16 + (lane & 15); \
        int q = r * 4 + (kc ^ ((r >> 1) & 3)); \
        a[mf] = *(const bf16x8*)(sA + ((BUF) * 2 + (KS)) * 8192 + q * 8); \
    } \
    if (LOADB) { \
        _Pragma("unroll") \
        for (int nf = 0; nf < 4; ++nf) { \
            int cr = wn * 64 + nf * 16 + (lane & 15); \
            int q = cr * 4 + (kc ^ ((cr >> 1) & 3)); \
            b[nf] = *(const bf16x8*)(sB + ((BUF) * 2 + (KS)) * 8192 + q * 8); \
        } \
    } \
    STAGE; \
    __builtin_amdgcn_s_barrier(); \
    __builtin_amdgcn_s_setprio(1); \
    _Pragma("unroll") \
    for (int mf = 0; mf < 4; ++mf) { \
        _Pragma("unroll") \
        for (int nf = 0; nf < 4; ++nf) \
            acc[(MH) * 4 + mf][nf] = __builtin_amdgcn_mfma_f32_16x16x32_bf16( \
                a[mf], b[nf], acc[(MH) * 4 + mf][nf], 0, 0, 0); \
    } \
    __builtin_amdgcn_s_setprio(0); \
    WAIT; \
    __builtin_amdgcn_s_barrier(); \
} while (0)

__global__ __launch_bounds__(512, 2)
void qkv_gemm8(const bf16_t* __restrict__ xb, const bf16_t* __restrict__ wb,
               float* __restrict__ out)
{
    extern __shared__ __attribute__((aligned(16))) char smem_raw[];
    bf16_t* sA = (bf16_t*)smem_raw;                 // [2 buf][2 kh][8192]  64 KiB
    bf16_t* sB = (bf16_t*)(smem_raw + 65536);       // [2 buf][2 kh][8192]  64 KiB

    const int tid  = threadIdx.x;
    const int lane = tid & 63;
    const int wid  = tid >> 6;     // 0..7
    const int wm   = wid >> 2;     // 0..1 (128-row half)
    const int wn   = wid & 3;      // 0..3 (64-col quarter)
    const int kc   = lane >> 4;    // frag k-chunk 0..3

    // L2-cooperative mapping (r6): each XCD owns an 8-row bm stripe, bn-major.
    const int xcd = blockIdx.x & 7;
    const int i   = blockIdx.x >> 3;       // 0..191
    const int bm  = xcd * 8 + (i & 7);
    const int bn  = i >> 3;                // 0..23
    const int m0 = bm * BM, n0 = bn * BN;

    // pre-swizzled staging sources (linear LDS dest + swizzled global source)
    const int r0  = tid >> 2;
    const int cl0 = (tid & 3) ^ ((r0 >> 1) & 3);
    const bf16_t* srcA0 = xb + (size_t)(m0 + r0) * Kk + cl0 * 8;
    const bf16_t* srcA1 = srcA0 + (size_t)128 * Kk;
    const bf16_t* srcB0 = wb + (size_t)(n0 + r0) * Kk + cl0 * 8;
    const bf16_t* srcB1 = srcB0 + (size_t)128 * Kk;

    bf16x8 b[4];
    f32x4 acc[8][4] = {};

    // prologue: stage buf0 (both kh) + buf1 kh0; confirm buf0
    STAGE_A(0, 0, 0);  STAGE_B(0, 0, 0);
    STAGE_A(0, 1, 32); STAGE_B(0, 1, 32);
    STAGE_A(1, 0, 64); STAGE_B(1, 0, 64);
    W_V4;
    __builtin_amdgcn_s_barrier();

    // 16 octets; stages use wrapped offsets so the tail stays uniform
#pragma unroll 1
    for (int it = 0; it < NITER; ++it) {
        const int kb = it * 128;
        PHASE(0, 0, 0, 1, STAGE_A(1, 1, (kb +  96) & 2047), W_NOW);
        PHASE(0, 0, 1, 0, STAGE_B(1, 1, (kb +  96) & 2047), W_NOW);
        PHASE(0, 1, 0, 1, STAGE_A(0, 0, (kb + 128) & 2047), W_NOW);
        PHASE(0, 1, 1, 0, STAGE_B(0, 0, (kb + 128) & 2047), W_V4);
        PHASE(1, 0, 0, 1, STAGE_A(0, 1, (kb + 160) & 2047), W_NOW);
        PHASE(1, 0, 1, 0, STAGE_B(0, 1, (kb + 160) & 2047), W_NOW);
        PHASE(1, 1, 0, 1, STAGE_A(1, 0, (kb + 192) & 2047), W_NOW);
        PHASE(1, 1, 1, 0, STAGE_B(1, 0, (kb + 192) & 2047), W_V4);
    }

    // drain in-flight (wrapped-junk) GLL before exit (LDS reuse hazard)
    asm volatile("s_waitcnt vmcnt(0)" ::: "memory");

    // epilogue: block cols span 2 heads (DK=128); per-wave head constant.
    // nt stores, line-contiguous (mh,mf,r,nf) order.
    const int which = n0 >> 11;
    const int hh    = ((n0 & (Ee - 1)) >> 7) + (wn >> 1);
    const int bbx   = m0 >> 12;
    const int s0    = (m0 & (Ss - 1)) + wm * 128;
    float* obase = out + (((size_t)(which * Bb + bbx) * Hh + hh) * Ss + s0) * Dk + (wn & 1) * 64;

#pragma unroll
    for (int mh = 0; mh < 2; ++mh)
#pragma unroll
        for (int mf = 0; mf < 4; ++mf)
#pragma unroll
            for (int r = 0; r < 4; ++r)
#pragma unroll
                for (int nf = 0; nf < 4; ++nf) {
                    const int row = mh * 64 + mf * 16 + (lane >> 4) * 4 + r;
                    const int col = nf * 16 + (lane & 15);
                    __builtin_nontemporal_store(acc[mh * 4 + mf][nf][r],
                                                &obase[(size_t)row * Dk + col]);
                }
}

// ------------------------------------------- fallback (fp32 reg staging)
constexpr int FTM = 128, FTN = 128, FTK = 64;
constexpr int FNKT = Kk / FTK;

__global__ __launch_bounds__(256, 2)
void qkv_gemm_fb(const float* __restrict__ x, const float* __restrict__ w,
                 float* __restrict__ out)
{
    __shared__ __attribute__((aligned(16))) bf16_t lA[2][FTM * FTK];
    __shared__ __attribute__((aligned(16))) bf16_t lB[2][FTN * FTK];

    const int tid = threadIdx.x, lane = tid & 63, wid = tid >> 6;
    const int wm = wid >> 1, wn = wid & 1;
    const int n0 = blockIdx.x * FTN, m0 = blockIdx.y * FTM;
    f32x4 ra[8], rb[8];

    auto load_regs = [&](int kt) {
        const int k0 = kt * FTK;
#pragma unroll
        for (int i = 0; i < 4; ++i) {
            const int c = tid + i * 256, row = c >> 3, cir = c & 7;
            const float* pa = x + (size_t)(m0 + row) * Kk + k0 + cir * 8;
            const float* pb = w + (size_t)(n0 + row) * Kk + k0 + cir * 8;
            ra[i*2+0] = *(const f32x4*)(pa); ra[i*2+1] = *(const f32x4*)(pa+4);
            rb[i*2+0] = *(const f32x4*)(pb); rb[i*2+1] = *(const f32x4*)(pb+4);
        }
    };
    auto store_lds = [&](int buf) {
#pragma unroll
        for (int i = 0; i < 4; ++i) {
            const int c = tid + i * 256, row = c >> 3, cir = c & 7;
            const int chunk = row * 8 + (cir ^ (row & 7));
            bf16x8 va, vb;
#pragma unroll
            for (int j = 0; j < 4; ++j) {
                va[j] = (bf16_t)ra[i*2+0][j]; va[j+4] = (bf16_t)ra[i*2+1][j];
                vb[j] = (bf16_t)rb[i*2+0][j]; vb[j+4] = (bf16_t)rb[i*2+1][j];
            }
            *(bf16x8*)(&lA[buf][chunk*8]) = va;
            *(bf16x8*)(&lB[buf][chunk*8]) = vb;
        }
    };
    f32x4 acc[4][4] = {};
    auto compute = [&](int buf) {
#pragma unroll
        for (int ks = 0; ks < 2; ++ks) {
            bf16x8 af[4], bfr[4];
#pragma unroll
            for (int mi = 0; mi < 4; ++mi) {
                const int row = wm*64 + mi*16 + (lane & 15);
                const int cir = ks*4 + (lane >> 4);
                af[mi] = *(const bf16x8*)(&lA[buf][(row*8 + (cir ^ (row & 7)))*8]);
            }
#pragma unroll
            for (int ni = 0; ni < 4; ++ni) {
                const int row = wn*64 + ni*16 + (lane & 15);
                const int cir = ks*4 + (lane >> 4);
                bfr[ni] = *(const bf16x8*)(&lB[buf][(row*8 + (cir ^ (row & 7)))*8]);
            }
#pragma unroll
            for (int mi = 0; mi < 4; ++mi)
#pragma unroll
                for (int ni = 0; ni < 4; ++ni)
                    acc[mi][ni] = __builtin_amdgcn_mfma_f32_16x16x32_bf16(af[mi], bfr[ni], acc[mi][ni], 0, 0, 0);
        }
    };

    load_regs(0); store_lds(0);
    int cur = 0;
#pragma unroll 1
    for (int kt = 0; kt < FNKT; ++kt) {
        __syncthreads();
        if (kt + 1 < FNKT) load_regs(kt + 1);
        compute(cur);
        if (kt + 1 < FNKT) store_lds(cur ^ 1);
        cur ^= 1;
    }
    const int b = m0 / Ss, s0g = m0 % Ss;
    const int which = n0 >> 11, h = (n0 & (Ee - 1)) >> 7;
    float* obase = out + ((size_t)((which * Bb + b) * Hh + h) * Ss + s0g) * Dk;
#pragma unroll
    for (int mi = 0; mi < 4; ++mi)
#pragma unroll
        for (int ni = 0; ni < 4; ++ni)
#pragma unroll
            for (int r = 0; r < 4; ++r) {
                const int rowL = wm*64 + mi*16 + (lane >> 4)*4 + r;
                const int colL = wn*64 + ni*16 + (lane & 15);
                obase[(size_t)rowL * Dk + colL] = acc[mi][ni][r];
            }
}

// ---------------------------------------------------------------- launcher
extern "C" void kernel_launch(void* const* d_in, const int* in_sizes, int n_in,
                              void* d_out, int out_size, void* d_ws, size_t ws_size,
                              hipStream_t stream) {
    const float* x = (const float*)d_in[0];
    const float* w = (const float*)d_in[1];
    float* out = (float*)d_out;

    const size_t xb_bytes = (size_t)Mm * Kk * 2;
    const size_t wb_bytes = (size_t)Nn * Kk * 2;

    if (ws_size >= xb_bytes + wb_bytes) {
        bf16_t* xb = (bf16_t*)d_ws;
        bf16_t* wb = (bf16_t*)((char*)d_ws + xb_bytes);
        cast_f32_to_bf16<<<2048, 256, 0, stream>>>(x, w, xb, wb);
        hipFuncSetAttribute((const void*)qkv_gemm8,
                            hipFuncAttributeMaxDynamicSharedMemorySize, 131072);
        qkv_gemm8<<<NWG, 512, 131072, stream>>>(xb, wb, out);
    } else {
        dim3 grid(Nn / FTN, Mm / FTM);
        qkv_gemm_fb<<<grid, dim3(256), 0, stream>>>(x, w, out);
    }
}

// Round 13
// 426.331 us; speedup vs baseline: 1.1272x; 1.0220x over previous
//
#include <hip/hip_runtime.h>
#include <hip/hip_bf16.h>

// LinearPreMix: qkv = x @ W_qkv^T, split to q,k,v, reshape [B,S,E]->[B,H,S,DK]
// Pass 1: cast x,W fp32->bf16 into d_ws.
// Pass 2: r13 — PERSISTENT version of r12 (grid 256 = 1 block/CU, 6 tiles per
//         block). r12's octet schedule kept bit-for-bit: wrapped tail stages
//         (k->0,32,64 at it==15) become real next-tile staging (B pointer
//         switch, A unchanged). Boundary = grouped full-line nt store burst
//         directly from acc (r3's failure was half-line pairs -> RMW; quads
//         of nf at fixed row are full 128B lines). Removes 5 rounds of
//         drain/exit/relaunch/prologue.

constexpr int Bb = 4, Ss = 4096, Ee = 2048, Hh = 16, Dk = 128;
constexpr int Mm = Bb * Ss;   // 16384
constexpr int Nn = 3 * Ee;    // 6144
constexpr int Kk = Ee;        // 2048

typedef __bf16 bf16_t;
typedef __bf16 bf16x8 __attribute__((ext_vector_type(8)));
typedef float  f32x4  __attribute__((ext_vector_type(4)));

// ---------------------------------------------------------------- cast pass
__global__ __launch_bounds__(256)
void cast_f32_to_bf16(const float* __restrict__ x, const float* __restrict__ w,
                      bf16_t* __restrict__ xb, bf16_t* __restrict__ wb)
{
    const long XG = (long)Mm * Kk / 8;
    const long TG = XG + (long)Nn * Kk / 8;
    const long stride = (long)gridDim.x * blockDim.x;
    for (long g = (long)blockIdx.x * blockDim.x + threadIdx.x; g < TG; g += stride) {
        const float* s; bf16_t* d;
        if (g < XG) { s = x + g * 8;        d = xb + g * 8; }
        else        { s = w + (g - XG) * 8; d = wb + (g - XG) * 8; }
        f32x4 lo = *(const f32x4*)s;
        f32x4 hi = *(const f32x4*)(s + 4);
        bf16x8 o;
#pragma unroll
        for (int j = 0; j < 4; ++j) { o[j] = (bf16_t)lo[j]; o[j + 4] = (bf16_t)hi[j]; }
        *(bf16x8*)d = o;
    }
}

// -------------------------------------------- persistent 8-phase 256² GEMM
constexpr int BM = 256, BN = 256;
constexpr long BSTEP = (long)1024 * Kk;   // 4 bn-panels of 256 rows

#define GLL16(GSRC, LDST) \
  __builtin_amdgcn_global_load_lds((const __attribute__((address_space(1))) void*)(GSRC), \
                                   (__attribute__((address_space(3))) void*)(LDST), 16, 0, 0)

#define STAGE_A(BUF, KH, KOFS) do { \
    bf16_t* _d = sA + ((BUF) * 2 + (KH)) * 8192 + wid * 512; \
    GLL16(srcA0 + (KOFS), _d); \
    GLL16(srcA1 + (KOFS), _d + 4096); \
} while (0)

#define STAGE_B(BUF, KH, P0, P1, KOFS) do { \
    bf16_t* _d = sB + ((BUF) * 2 + (KH)) * 8192 + wid * 512; \
    GLL16((P0) + (KOFS), _d); \
    GLL16((P1) + (KOFS), _d + 4096); \
} while (0)

#define W_NOW ((void)0)
#define W_V4  asm volatile("s_waitcnt vmcnt(4)" ::: "memory")

// phase (r12, no sched_barrier pins, no bulk lgkmcnt):
// ds-reads | stage | barrier | setprio+MFMA | counted vmcnt | barrier
#define PHASE(BUF, KS, MH, LOADB, STAGE, WAIT) do { \
    bf16x8 a[4]; \
    _Pragma("unroll") \
    for (int mf = 0; mf < 4; ++mf) { \
        int r = wm * 128 + (MH) * 64 + mf * 16 + (lane & 15); \
        int q = r * 4 + (kc ^ ((r >> 1) & 3)); \
        a[mf] = *(const bf16x8*)(sA + ((BUF) * 2 + (KS)) * 8192 + q * 8); \
    } \
    if (LOADB) { \
        _Pragma("unroll") \
        for (int nf = 0; nf < 4; ++nf) { \
            int cr = wn * 64 + nf * 16 + (lane & 15); \
            int q = cr * 4 + (kc ^ ((cr >> 1) & 3)); \
            b[nf] = *(const bf16x8*)(sB + ((BUF) * 2 + (KS)) * 8192 + q * 8); \
        } \
    } \
    STAGE; \
    __builtin_amdgcn_s_barrier(); \
    __builtin_amdgcn_s_setprio(1); \
    _Pragma("unroll") \
    for (int mf = 0; mf < 4; ++mf) { \
        _Pragma("unroll") \
        for (int nf = 0; nf < 4; ++nf) \
            acc[(MH) * 4 + mf][nf] = __builtin_amdgcn_mfma_f32_16x16x32_bf16( \
                a[mf], b[nf], acc[(MH) * 4 + mf][nf], 0, 0, 0); \
    } \
    __builtin_amdgcn_s_setprio(0); \
    WAIT; \
    __builtin_amdgcn_s_barrier(); \
} while (0)

__global__ __launch_bounds__(512, 2)
void qkv_pers(const bf16_t* __restrict__ xb, const bf16_t* __restrict__ wb,
              float* __restrict__ out)
{
    extern __shared__ __attribute__((aligned(16))) char smem_raw[];
    bf16_t* sA = (bf16_t*)smem_raw;                 // [2 buf][2 kh][8192]  64 KiB
    bf16_t* sB = (bf16_t*)(smem_raw + 65536);       // [2 buf][2 kh][8192]  64 KiB

    const int tid  = threadIdx.x;
    const int lane = tid & 63;
    const int wid  = tid >> 6;     // 0..7
    const int wm   = wid >> 2;     // 0..1 (128-row half)
    const int wn   = wid & 3;      // 0..3 (64-col quarter)
    const int kc   = lane >> 4;    // frag k-chunk 0..3

    // persistent mapping: 256 blocks = 8 XCD x 32 CU; fixed bm stripe per XCD
    // (L2-coop, r6); bn walks bn0 + 4t over 6 tiles.
    const int xcd = blockIdx.x & 7;
    const int cu  = blockIdx.x >> 3;       // 0..31
    const int bm  = xcd * 8 + (cu >> 2);   // 0..63
    const int bn0 = cu & 3;                // 0..3
    const int m0  = bm * BM;

    // pre-swizzled staging sources (linear LDS dest + swizzled global source)
    const int r0  = tid >> 2;
    const int cl0 = (tid & 3) ^ ((r0 >> 1) & 3);
    const bf16_t* srcA0 = xb + (size_t)(m0 + r0) * Kk + cl0 * 8;
    const bf16_t* srcA1 = srcA0 + (size_t)128 * Kk;
    const bf16_t* cB0 = wb + (size_t)(bn0 * 256 + r0) * Kk + cl0 * 8;
    const bf16_t* cB1 = cB0 + (size_t)128 * Kk;
    const bf16_t* nB0 = cB0 + BSTEP;
    const bf16_t* nB1 = cB1 + BSTEP;

    const int bbx  = m0 >> 12;
    const int s0   = (m0 & (Ss - 1)) + wm * 128;

    bf16x8 b[4];
    f32x4 acc[8][4] = {};

    // prologue: stage buf0 (both kh) + buf1 kh0; confirm buf0
    STAGE_A(0, 0, 0);  STAGE_B(0, 0, cB0, cB1, 0);
    STAGE_A(0, 1, 32); STAGE_B(0, 1, cB0, cB1, 32);
    STAGE_A(1, 0, 64); STAGE_B(1, 0, cB0, cB1, 64);
    W_V4;
    __builtin_amdgcn_s_barrier();

#pragma unroll 1
    for (int t = 0; t < 6; ++t) {
#pragma unroll 1
        for (int it = 0; it < 16; ++it) {
            const int kb = it * 128;
            // stages at kb+128/160/192 wrap to next tile's k=0/32/64 at it==15:
            // A continues the same panel; B must switch to the next panel.
            const bf16_t* tb0 = (it == 15) ? nB0 : cB0;
            const bf16_t* tb1 = (it == 15) ? nB1 : cB1;
            PHASE(0, 0, 0, 1, STAGE_A(1, 1, kb + 96),                     W_NOW);
            PHASE(0, 0, 1, 0, STAGE_B(1, 1, cB0, cB1, kb + 96),           W_NOW);
            PHASE(0, 1, 0, 1, STAGE_A(0, 0, (kb + 128) & 2047),           W_NOW);
            PHASE(0, 1, 1, 0, STAGE_B(0, 0, tb0, tb1, (kb + 128) & 2047), W_V4);
            PHASE(1, 0, 0, 1, STAGE_A(0, 1, (kb + 160) & 2047),           W_NOW);
            PHASE(1, 0, 1, 0, STAGE_B(0, 1, tb0, tb1, (kb + 160) & 2047), W_NOW);
            PHASE(1, 1, 0, 1, STAGE_A(1, 0, (kb + 192) & 2047),           W_NOW);
            PHASE(1, 1, 1, 0, STAGE_B(1, 0, tb0, tb1, (kb + 192) & 2047), W_V4);
        }

        // ---- tile boundary: full-line nt store burst from acc, zero, advance
        {
            const int n0    = (bn0 + 4 * t) * BN;
            const int which = n0 >> 11;
            const int hh    = ((n0 & (Ee - 1)) >> 7) + (wn >> 1);
            float* obase = out + (((size_t)(which * Bb + bbx) * Hh + hh) * Ss + s0) * Dk
                         + (wn & 1) * 64;
#pragma unroll
            for (int mh = 0; mh < 2; ++mh)
#pragma unroll
                for (int mf = 0; mf < 4; ++mf)
#pragma unroll
                    for (int r = 0; r < 4; ++r)
#pragma unroll
                        for (int nf = 0; nf < 4; ++nf) {
                            const int row = mh * 64 + mf * 16 + (lane >> 4) * 4 + r;
                            const int col = nf * 16 + (lane & 15);
                            __builtin_nontemporal_store(acc[mh * 4 + mf][nf][r],
                                                        &obase[(size_t)row * Dk + col]);
                        }
#pragma unroll
            for (int i = 0; i < 8; ++i)
#pragma unroll
                for (int nf = 0; nf < 4; ++nf)
                    acc[i][nf] = f32x4{0.f, 0.f, 0.f, 0.f};

            cB0 = nB0; cB1 = nB1;
            if (t == 4) { nB0 -= 5 * BSTEP; nB1 -= 5 * BSTEP; }  // wrap: junk tail of t=5
            else        { nB0 += BSTEP;     nB1 += BSTEP;     }
        }
    }

    // drain remaining (junk) GLLs and stores before exit
    asm volatile("s_waitcnt vmcnt(0)" ::: "memory");
}

// ------------------------------------------- fallback (fp32 reg staging)
constexpr int FTM = 128, FTN = 128, FTK = 64;
constexpr int FNKT = Kk / FTK;

__global__ __launch_bounds__(256, 2)
void qkv_gemm_fb(const float* __restrict__ x, const float* __restrict__ w,
                 float* __restrict__ out)
{
    __shared__ __attribute__((aligned(16))) bf16_t lA[2][FTM * FTK];
    __shared__ __attribute__((aligned(16))) bf16_t lB[2][FTN * FTK];

    const int tid = threadIdx.x, lane = tid & 63, wid = tid >> 6;
    const int wm = wid >> 1, wn = wid & 1;
    const int n0 = blockIdx.x * FTN, m0 = blockIdx.y * FTM;
    f32x4 ra[8], rb[8];

    auto load_regs = [&](int kt) {
        const int k0 = kt * FTK;
#pragma unroll
        for (int i = 0; i < 4; ++i) {
            const int c = tid + i * 256, row = c >> 3, cir = c & 7;
            const float* pa = x + (size_t)(m0 + row) * Kk + k0 + cir * 8;
            const float* pb = w + (size_t)(n0 + row) * Kk + k0 + cir * 8;
            ra[i*2+0] = *(const f32x4*)(pa); ra[i*2+1] = *(const f32x4*)(pa+4);
            rb[i*2+0] = *(const f32x4*)(pb); rb[i*2+1] = *(const f32x4*)(pb+4);
        }
    };
    auto store_lds = [&](int buf) {
#pragma unroll
        for (int i = 0; i < 4; ++i) {
            const int c = tid + i * 256, row = c >> 3, cir = c & 7;
            const int chunk = row * 8 + (cir ^ (row & 7));
            bf16x8 va, vb;
#pragma unroll
            for (int j = 0; j < 4; ++j) {
                va[j] = (bf16_t)ra[i*2+0][j]; va[j+4] = (bf16_t)ra[i*2+1][j];
                vb[j] = (bf16_t)rb[i*2+0][j]; vb[j+4] = (bf16_t)rb[i*2+1][j];
            }
            *(bf16x8*)(&lA[buf][chunk*8]) = va;
            *(bf16x8*)(&lB[buf][chunk*8]) = vb;
        }
    };
    f32x4 acc[4][4] = {};
    auto compute = [&](int buf) {
#pragma unroll
        for (int ks = 0; ks < 2; ++ks) {
            bf16x8 af[4], bfr[4];
#pragma unroll
            for (int mi = 0; mi < 4; ++mi) {
                const int row = wm*64 + mi*16 + (lane & 15);
                const int cir = ks*4 + (lane >> 4);
                af[mi] = *(const bf16x8*)(&lA[buf][(row*8 + (cir ^ (row & 7)))*8]);
            }
#pragma unroll
            for (int ni = 0; ni < 4; ++ni) {
                const int row = wn*64 + ni*16 + (lane & 15);
                const int cir = ks*4 + (lane >> 4);
                bfr[ni] = *(const bf16x8*)(&lB[buf][(row*8 + (cir ^ (row & 7)))*8]);
            }
#pragma unroll
            for (int mi = 0; mi < 4; ++mi)
#pragma unroll
                for (int ni = 0; ni < 4; ++ni)
                    acc[mi][ni] = __builtin_amdgcn_mfma_f32_16x16x32_bf16(af[mi], bfr[ni], acc[mi][ni], 0, 0, 0);
        }
    };

    load_regs(0); store_lds(0);
    int cur = 0;
#pragma unroll 1
    for (int kt = 0; kt < FNKT; ++kt) {
        __syncthreads();
        if (kt + 1 < FNKT) load_regs(kt + 1);
        compute(cur);
        if (kt + 1 < FNKT) store_lds(cur ^ 1);
        cur ^= 1;
    }
    const int b = m0 / Ss, s0g = m0 % Ss;
    const int which = n0 >> 11, h = (n0 & (Ee - 1)) >> 7;
    float* obase = out + ((size_t)((which * Bb + b) * Hh + h) * Ss + s0g) * Dk;
#pragma unroll
    for (int mi = 0; mi < 4; ++mi)
#pragma unroll
        for (int ni = 0; ni < 4; ++ni)
#pragma unroll
            for (int r = 0; r < 4; ++r) {
                const int rowL = wm*64 + mi*16 + (lane >> 4)*4 + r;
                const int colL = wn*64 + ni*16 + (lane & 15);
                obase[(size_t)rowL * Dk + colL] = acc[mi][ni][r];
            }
}

// ---------------------------------------------------------------- launcher
extern "C" void kernel_launch(void* const* d_in, const int* in_sizes, int n_in,
                              void* d_out, int out_size, void* d_ws, size_t ws_size,
                              hipStream_t stream) {
    const float* x = (const float*)d_in[0];
    const float* w = (const float*)d_in[1];
    float* out = (float*)d_out;

    const size_t xb_bytes = (size_t)Mm * Kk * 2;
    const size_t wb_bytes = (size_t)Nn * Kk * 2;

    if (ws_size >= xb_bytes + wb_bytes) {
        bf16_t* xb = (bf16_t*)d_ws;
        bf16_t* wb = (bf16_t*)((char*)d_ws + xb_bytes);
        cast_f32_to_bf16<<<2048, 256, 0, stream>>>(x, w, xb, wb);
        hipFuncSetAttribute((const void*)qkv_pers,
                            hipFuncAttributeMaxDynamicSharedMemorySize, 131072);
        qkv_pers<<<256, 512, 131072, stream>>>(xb, wb, out);
    } else {
        dim3 grid(Nn / FTN, Mm / FTM);
        qkv_gemm_fb<<<grid, dim3(256), 0, stream>>>(x, w, out);
    }
}